// Round 5
// baseline (194.930 us; speedup 1.0000x reference)
//
#include <hip/hip_runtime.h>

#define N_SPIKES 16384
#define N_UNITS  256
#define N_NEIGHB 128
#define RANK     5
#define NC       64
#define NC_OBS   12
#define N_CAND   10
#define DD       60                 // RANK * NC_OBS
#define DD4      15                 // DD / 4
#define OUT_COLS 61
#define OUT_SIZE (N_UNITS * OUT_COLS)   // 15616
#define SPIKE_BLOCKS 256
#define LIST_CAP 480

// ---------------------------------------------------------------------------
// Kernel P: fused nu-gather + matvec (unchanged from R4 — known correct).
//   w[h,u] = Coo_inv[h] @ nu,  b = log_prop[u] - 0.5 * nu.w
// ---------------------------------------------------------------------------
__global__ __launch_bounds__(128) void precompute_kernel(
    const float* __restrict__ mu, const float* __restrict__ Coo_inv,
    const int* __restrict__ obs_ix, const float* __restrict__ log_prop,
    float* __restrict__ w_buf, float* __restrict__ b_buf)
{
    __shared__ float tile[128 * 61];

    const int h    = blockIdx.x >> 1;
    const int tid  = threadIdx.x;
    const int lane = tid & 63;
    const int wave = tid >> 6;
    const int u    = (blockIdx.x & 1) * 128 + wave * 64 + lane;
    const int p    = h * N_UNITS + u;

    int so[NC_OBS];
#pragma unroll
    for (int j = 0; j < NC_OBS; ++j) so[j] = obs_ix[h * NC_OBS + j];

    const float* __restrict__ mub = mu + u * (RANK * NC);
    float* tl = &tile[tid * 61];
#pragma unroll
    for (int d = 0; d < DD; ++d) {
        const int r = d / NC_OBS;
        const int j = d - r * NC_OBS;
        tl[d] = mub[r * NC + so[j]];
    }

    float wreg[DD];
#pragma unroll
    for (int d = 0; d < DD; ++d) wreg[d] = 0.f;

    const float* __restrict__ C = Coo_inv + h * DD * DD;
    for (int e = 0; e < DD; ++e) {
        const float nu_e = tl[e];
        const float* __restrict__ Crow = C + e * DD;
#pragma unroll
        for (int d = 0; d < DD; ++d)
            wreg[d] = fmaf(Crow[d], nu_e, wreg[d]);
    }

    float q2 = 0.f;
#pragma unroll
    for (int d = 0; d < DD; ++d) q2 += wreg[d] * tl[d];

#pragma unroll
    for (int k = 0; k < DD4; ++k) {
        float4 o;
        o.x = wreg[4*k+0]; o.y = wreg[4*k+1];
        o.z = wreg[4*k+2]; o.w = wreg[4*k+3];
        ((float4*)w_buf)[p * DD4 + k] = o;
    }
    b_buf[p] = log_prop[u] - 0.5f * q2;
}

// ---------------------------------------------------------------------------
// Kernel S: h-bucketed spike pass.  2 blocks per h (spike-index parity).
// Each block: scan nid -> LDS spike list; stage w-table row h (60 KB) +
// b row into LDS; process spikes with all candidate reads from LDS
// (ds_read_b128, rows 240 B = 16 B aligned); LDS-atomic accumulate;
// flush to per-block partials (deterministic, no global atomic storm).
// LDS ~127 KB -> 1 block/CU, 8 waves.
// ---------------------------------------------------------------------------
__global__ __launch_bounds__(512, 2) void spike_kernel(
    const float* __restrict__ features, const float* __restrict__ noise_lp,
    const int* __restrict__ cands, const int* __restrict__ nid,
    const float* __restrict__ w_buf, const float* __restrict__ b_buf,
    float* __restrict__ partials)
{
    __shared__ float wtab[N_UNITS * DD];   // 61440 B, row stride 60 (16B-aligned)
    __shared__ float acc[OUT_SIZE];        // 62464 B
    __shared__ float bs[N_UNITS];          // 1024 B
    __shared__ int   list[LIST_CAP];       // 1920 B
    __shared__ int   lcount;

    const int tid    = threadIdx.x;
    const int h      = blockIdx.x >> 1;
    const int parity = blockIdx.x & 1;

    if (tid == 0) lcount = 0;
    for (int i = tid; i < OUT_SIZE; i += 512) acc[i] = 0.f;
    __syncthreads();   // lcount/acc init visible

    // phase A: scan nid (64 KB, coalesced, L1/L2-broadcast), build list
#pragma unroll
    for (int i = 0; i < N_SPIKES / 512; ++i) {
        const int n = i * 512 + tid;
        if (nid[n] == h && (n & 1) == parity) {
            const int p = atomicAdd(&lcount, 1);
            if (p < LIST_CAP) list[p] = n;
        }
    }

    // phase B: stage w-table + b row for this h (coalesced float4)
    const float4* __restrict__ wrow = (const float4*)(w_buf + (size_t)h * N_UNITS * DD);
    float4* __restrict__ wt4 = (float4*)wtab;
    for (int i = tid; i < N_UNITS * DD4; i += 512) wt4[i] = wrow[i];
    for (int i = tid; i < N_UNITS; i += 512) bs[i] = b_buf[h * N_UNITS + i];

    __syncthreads();
    const int cnt = (lcount < LIST_CAP) ? lcount : LIST_CAP;

    // phase C: 16-lane float4 groups, 4 spikes per wave per iteration
    const int lane = tid & 63;
    const int wave = tid >> 6;
    const int l = lane & 15;
    const int s = lane >> 4;
    const bool dimlane = (l < DD4);
    const float nlp = noise_lp[0];
    const float4* __restrict__ f4 = (const float4*)features;
    const float4 z4 = {0.f, 0.f, 0.f, 0.f};

    for (int pos = wave * 4 + s; pos < cnt; pos += 32) {
        const int n = list[pos];
        const float4 xf = dimlane ? f4[n * DD4 + l] : z4;

        int uc[N_CAND];
#pragma unroll
        for (int c = 0; c < N_CAND; ++c) uc[c] = cands[n * N_CAND + c];

        float ll[N_CAND];
#pragma unroll
        for (int c = 0; c < N_CAND; ++c) {
            const float4 wv = dimlane ? ((const float4*)wtab)[uc[c] * DD4 + l] : z4;
            float t = wv.x*xf.x + wv.y*xf.y + wv.z*xf.z + wv.w*xf.w;
            t += __shfl_xor(t, 8, 64);
            t += __shfl_xor(t, 4, 64);
            t += __shfl_xor(t, 2, 64);
            t += __shfl_xor(t, 1, 64);
            ll[c] = bs[uc[c]] + t;
        }

        float m = nlp;
#pragma unroll
        for (int c = 0; c < N_CAND; ++c) m = fmaxf(m, ll[c]);
        float ssum = __expf(nlp - m);
        float qv[N_CAND];
#pragma unroll
        for (int c = 0; c < N_CAND; ++c) { qv[c] = __expf(ll[c] - m); ssum += qv[c]; }
        const float inv = 1.f / ssum;

#pragma unroll
        for (int c = 0; c < N_CAND; ++c) {
            const float q = qv[c] * inv;
            const int ub = uc[c] * OUT_COLS;
            if (dimlane) {
                const int a = ub + 1 + l * 4;
                atomicAdd(&acc[a + 0], q * xf.x);
                atomicAdd(&acc[a + 1], q * xf.y);
                atomicAdd(&acc[a + 2], q * xf.z);
                atomicAdd(&acc[a + 3], q * xf.w);
            } else if (l == DD4) {        // lane 15 of group: count column
                atomicAdd(&acc[ub], q);
            }
        }
    }

    __syncthreads();
    float* __restrict__ pb = partials + (size_t)blockIdx.x * OUT_SIZE;
    for (int i = tid; i < OUT_SIZE; i += 512) pb[i] = acc[i];
}

// ---------------------------------------------------------------------------
// Kernel 3: reduce 256 partial buffers -> d_out (overwrites: no memset needed)
// ---------------------------------------------------------------------------
__global__ __launch_bounds__(256) void reduce_kernel(
    const float* __restrict__ partials, float* __restrict__ out)
{
    __shared__ float red[256];
    const int tid = threadIdx.x;
    const int col = blockIdx.x * 64 + (tid & 63);
    const int grp = tid >> 6;

    float s = 0.f;
#pragma unroll 8
    for (int b = grp; b < SPIKE_BLOCKS; b += 4)
        s += partials[(size_t)b * OUT_SIZE + col];

    red[tid] = s;
    __syncthreads();
    if (tid < 64)
        out[col] = (red[tid] + red[tid + 64]) + (red[tid + 128] + red[tid + 192]);
}

extern "C" void kernel_launch(void* const* d_in, const int* in_sizes, int n_in,
                              void* d_out, int out_size, void* d_ws, size_t ws_size,
                              hipStream_t stream) {
    const float* features    = (const float*)d_in[0];
    const float* mu          = (const float*)d_in[1];
    const float* Coo_inv     = (const float*)d_in[2];
    // d_in[3] = Coo_logdet : unused (cancels in softmax)
    const float* log_prop    = (const float*)d_in[4];
    const float* noise_lp    = (const float*)d_in[5];
    const int*   cands       = (const int*)d_in[6];
    const int*   nid         = (const int*)d_in[7];
    const int*   obs_ix      = (const int*)d_in[8];
    float* out = (float*)d_out;

    char* ws = (char*)d_ws;
    float* w_buf    = (float*)ws;                         // 128*256*60*4 = 7,864,320 B
    float* b_buf    = (float*)(ws + 7864320);             // 128*256*4    =   131,072 B
    float* partials = (float*)(ws + 7864320 + 131072);    // 256*15616*4  = 15,990,784 B

    precompute_kernel<<<256, 128, 0, stream>>>(mu, Coo_inv, obs_ix, log_prop,
                                               w_buf, b_buf);
    spike_kernel<<<SPIKE_BLOCKS, 512, 0, stream>>>(features, noise_lp, cands, nid,
                                                   w_buf, b_buf, partials);
    reduce_kernel<<<244, 256, 0, stream>>>(partials, out);
}

// Round 6
// 177.852 us; speedup vs baseline: 1.0960x; 1.0960x over previous
//
#include <hip/hip_runtime.h>

#define N_SPIKES 16384
#define N_UNITS  256
#define N_NEIGHB 128
#define RANK     5
#define NC       64
#define NC_OBS   12
#define N_CAND   10
#define DD       60                 // RANK * NC_OBS
#define DD4      15                 // DD / 4
#define OUT_COLS 61
#define OUT_SIZE (N_UNITS * OUT_COLS)   // 15616
#define N_REP    64

// ---------------------------------------------------------------------------
// Kernel P: fused nu-gather + matvec (unchanged — known correct).
//   w[h,u] = Coo_inv[h] @ nu,  b = log_prop[u] - 0.5 * nu.w
// ---------------------------------------------------------------------------
__global__ __launch_bounds__(128) void precompute_kernel(
    const float* __restrict__ mu, const float* __restrict__ Coo_inv,
    const int* __restrict__ obs_ix, const float* __restrict__ log_prop,
    float* __restrict__ w_buf, float* __restrict__ b_buf)
{
    __shared__ float tile[128 * 61];

    const int h    = blockIdx.x >> 1;
    const int tid  = threadIdx.x;
    const int lane = tid & 63;
    const int wave = tid >> 6;
    const int u    = (blockIdx.x & 1) * 128 + wave * 64 + lane;
    const int p    = h * N_UNITS + u;

    int so[NC_OBS];
#pragma unroll
    for (int j = 0; j < NC_OBS; ++j) so[j] = obs_ix[h * NC_OBS + j];

    const float* __restrict__ mub = mu + u * (RANK * NC);
    float* tl = &tile[tid * 61];
#pragma unroll
    for (int d = 0; d < DD; ++d) {
        const int r = d / NC_OBS;
        const int j = d - r * NC_OBS;
        tl[d] = mub[r * NC + so[j]];
    }

    float wreg[DD];
#pragma unroll
    for (int d = 0; d < DD; ++d) wreg[d] = 0.f;

    const float* __restrict__ C = Coo_inv + h * DD * DD;
    for (int e = 0; e < DD; ++e) {
        const float nu_e = tl[e];
        const float* __restrict__ Crow = C + e * DD;
#pragma unroll
        for (int d = 0; d < DD; ++d)
            wreg[d] = fmaf(Crow[d], nu_e, wreg[d]);
    }

    float q2 = 0.f;
#pragma unroll
    for (int d = 0; d < DD; ++d) q2 += wreg[d] * tl[d];

#pragma unroll
    for (int k = 0; k < DD4; ++k) {
        float4 o;
        o.x = wreg[4*k+0]; o.y = wreg[4*k+1];
        o.z = wreg[4*k+2]; o.w = wreg[4*k+3];
        ((float4*)w_buf)[p * DD4 + k] = o;
    }
    b_buf[p] = log_prop[u] - 0.5f * q2;
}

// ---------------------------------------------------------------------------
// Kernel S: 16-lane float4 groups; each group owns TWO spikes with all
// loads for both hoisted ahead of any use (~25 cache lines in flight per
// wave -> latency-bound BW rises ~10x).  256 blocks x 512 thr, 64 spikes
// per block (8 per wave).  LDS acc flushed via nonzero-skip atomics into
// 64 replicated tables (no 16 MB partials round-trip, no big reduce).
// ---------------------------------------------------------------------------
__global__ __launch_bounds__(512, 2) void spike_kernel(
    const float* __restrict__ features, const float* __restrict__ noise_lp,
    const int* __restrict__ cands, const int* __restrict__ nid,
    const float* __restrict__ w_buf, const float* __restrict__ b_buf,
    float* __restrict__ rep)
{
    __shared__ float acc[OUT_SIZE];
    const int tid = threadIdx.x;
    for (int i = tid; i < OUT_SIZE; i += 512) acc[i] = 0.f;

    const int lane = tid & 63;
    const int wave = tid >> 6;
    const int l = lane & 15;          // dim-chunk within group
    const int s = lane >> 4;          // group slot within wave
    const bool dimlane = (l < DD4);
    const float nlp = noise_lp[0];
    const float4* __restrict__ f4 = (const float4*)features;
    const float4* __restrict__ w4 = (const float4*)w_buf;
    const float4 z4 = {0.f, 0.f, 0.f, 0.f};

    const int base = blockIdx.x * 64 + wave * 8;
    const int n0 = base + s;          // spike A for this group
    const int n1 = base + 4 + s;      // spike B for this group

    // ---- wavefront of independent loads, round 1 ----
    const int h0 = nid[n0];
    const int h1 = nid[n1];
    const float4 xf0 = dimlane ? f4[n0 * DD4 + l] : z4;
    const float4 xf1 = dimlane ? f4[n1 * DD4 + l] : z4;
    int uc0[N_CAND], uc1[N_CAND];
#pragma unroll
    for (int c = 0; c < N_CAND; ++c) {
        uc0[c] = cands[n0 * N_CAND + c];
        uc1[c] = cands[n1 * N_CAND + c];
    }

    // ---- round 2: all 20 gathers + 20 bias loads issued together ----
    float4 wv0[N_CAND], wv1[N_CAND];
    float  bb0[N_CAND], bb1[N_CAND];
#pragma unroll
    for (int c = 0; c < N_CAND; ++c) {
        const int p0 = h0 * N_UNITS + uc0[c];
        const int p1 = h1 * N_UNITS + uc1[c];
        wv0[c] = dimlane ? w4[p0 * DD4 + l] : z4;
        wv1[c] = dimlane ? w4[p1 * DD4 + l] : z4;
        bb0[c] = b_buf[p0];
        bb1[c] = b_buf[p1];
    }

    // ---- compute: dot + 4-step 16-lane reduce, both spikes ----
    float ll0[N_CAND], ll1[N_CAND];
#pragma unroll
    for (int c = 0; c < N_CAND; ++c) {
        float t0 = wv0[c].x*xf0.x + wv0[c].y*xf0.y + wv0[c].z*xf0.z + wv0[c].w*xf0.w;
        float t1 = wv1[c].x*xf1.x + wv1[c].y*xf1.y + wv1[c].z*xf1.z + wv1[c].w*xf1.w;
        t0 += __shfl_xor(t0, 8, 64); t1 += __shfl_xor(t1, 8, 64);
        t0 += __shfl_xor(t0, 4, 64); t1 += __shfl_xor(t1, 4, 64);
        t0 += __shfl_xor(t0, 2, 64); t1 += __shfl_xor(t1, 2, 64);
        t0 += __shfl_xor(t0, 1, 64); t1 += __shfl_xor(t1, 1, 64);
        ll0[c] = bb0[c] + t0;
        ll1[c] = bb1[c] + t1;
    }

    float m0 = nlp, m1 = nlp;
#pragma unroll
    for (int c = 0; c < N_CAND; ++c) { m0 = fmaxf(m0, ll0[c]); m1 = fmaxf(m1, ll1[c]); }
    float s0 = __expf(nlp - m0), s1 = __expf(nlp - m1);
    float qv0[N_CAND], qv1[N_CAND];
#pragma unroll
    for (int c = 0; c < N_CAND; ++c) {
        qv0[c] = __expf(ll0[c] - m0); s0 += qv0[c];
        qv1[c] = __expf(ll1[c] - m1); s1 += qv1[c];
    }
    const float inv0 = 1.f / s0, inv1 = 1.f / s1;

    __syncthreads();   // acc zero-init complete

#pragma unroll
    for (int c = 0; c < N_CAND; ++c) {
        const float q0 = qv0[c] * inv0;
        const float q1 = qv1[c] * inv1;
        const int ub0 = uc0[c] * OUT_COLS;
        const int ub1 = uc1[c] * OUT_COLS;
        if (dimlane) {
            const int a0 = ub0 + 1 + l * 4;
            atomicAdd(&acc[a0 + 0], q0 * xf0.x);
            atomicAdd(&acc[a0 + 1], q0 * xf0.y);
            atomicAdd(&acc[a0 + 2], q0 * xf0.z);
            atomicAdd(&acc[a0 + 3], q0 * xf0.w);
            const int a1 = ub1 + 1 + l * 4;
            atomicAdd(&acc[a1 + 0], q1 * xf1.x);
            atomicAdd(&acc[a1 + 1], q1 * xf1.y);
            atomicAdd(&acc[a1 + 2], q1 * xf1.z);
            atomicAdd(&acc[a1 + 3], q1 * xf1.w);
        } else if (l == DD4) {        // count column, one lane per group
            atomicAdd(&acc[ub0], q0);
            atomicAdd(&acc[ub1], q1);
        }
    }

    __syncthreads();
    // flush: nonzero-skip atomics into one of 64 replicated tables
    float* __restrict__ r = rep + (size_t)(blockIdx.x & (N_REP - 1)) * OUT_SIZE;
    for (int i = tid; i < OUT_SIZE; i += 512) {
        const float v = acc[i];
        if (v != 0.f) atomicAdd(&r[i], v);
    }
}

// ---------------------------------------------------------------------------
// Kernel R: sum 64 replicas -> d_out.  61 blocks x 256 thr.
// ---------------------------------------------------------------------------
__global__ __launch_bounds__(256) void reduce_kernel(
    const float* __restrict__ rep, float* __restrict__ out)
{
    const int i = blockIdx.x * 256 + threadIdx.x;
    float s = 0.f;
#pragma unroll 8
    for (int r = 0; r < N_REP; ++r)
        s += rep[(size_t)r * OUT_SIZE + i];
    out[i] = s;
}

extern "C" void kernel_launch(void* const* d_in, const int* in_sizes, int n_in,
                              void* d_out, int out_size, void* d_ws, size_t ws_size,
                              hipStream_t stream) {
    const float* features    = (const float*)d_in[0];
    const float* mu          = (const float*)d_in[1];
    const float* Coo_inv     = (const float*)d_in[2];
    // d_in[3] = Coo_logdet : unused (cancels in softmax)
    const float* log_prop    = (const float*)d_in[4];
    const float* noise_lp    = (const float*)d_in[5];
    const int*   cands       = (const int*)d_in[6];
    const int*   nid         = (const int*)d_in[7];
    const int*   obs_ix      = (const int*)d_in[8];
    float* out = (float*)d_out;

    char* ws = (char*)d_ws;
    float* w_buf = (float*)ws;                         // 128*256*60*4 = 7,864,320 B
    float* b_buf = (float*)(ws + 7864320);             // 128*256*4    =   131,072 B
    float* rep   = (float*)(ws + 7864320 + 131072);    // 64*15616*4   = 3,997,696 B

    hipMemsetAsync(rep, 0, (size_t)N_REP * OUT_SIZE * sizeof(float), stream);
    precompute_kernel<<<256, 128, 0, stream>>>(mu, Coo_inv, obs_ix, log_prop,
                                               w_buf, b_buf);
    spike_kernel<<<256, 512, 0, stream>>>(features, noise_lp, cands, nid,
                                          w_buf, b_buf, rep);
    reduce_kernel<<<61, 256, 0, stream>>>(rep, out);
}